// Round 11
// baseline (384.349 us; speedup 1.0000x reference)
//
#include <hip/hip_runtime.h>
#include <math.h>

// Problem constants (B=4, S=4096, H=4096, E=64, top_k=8)
#define TOKENS 16384   // B*S
#define HDIM   4096
#define NEXP   64
#define TOPK   8

#define TAU 1.5e-4f    // certify margin; logit err RMS ~2e-6 -> TAU/2 = 37 sigma

typedef short bf16x8 __attribute__((ext_vector_type(8)));
typedef float f32x4  __attribute__((ext_vector_type(4)));

__device__ __forceinline__ unsigned bf16_rne(float f) {
    unsigned u = __float_as_uint(f);
    return (u + 0x7fffu + ((u >> 16) & 1u)) >> 16;
}
__device__ __forceinline__ float bf16_tof(unsigned h) { return __uint_as_float(h << 16); }

// ================= B pre-split: wgt fp32 -> 3 bf16 planes in d_ws ==============
__global__ __launch_bounds__(256) void bsplit_kernel(const float* __restrict__ wgt,
                                                     short* __restrict__ bsp,
                                                     int* __restrict__ cnt) {
    if (blockIdx.x == 0 && threadIdx.x == 0) *cnt = 0;   // reset recheck worklist
    const int base = 4 * (blockIdx.x * 256 + threadIdx.x);
    float4 w = *reinterpret_cast<const float4*>(wgt + base);
    float f[4] = {w.x, w.y, w.z, w.w};
    short h0[4], h1[4], h2[4];
#pragma unroll
    for (int e = 0; e < 4; ++e) {
        unsigned b0 = bf16_rne(f[e]); float r1 = f[e] - bf16_tof(b0);
        unsigned b1 = bf16_rne(r1);   float r2 = r1 - bf16_tof(b1);
        unsigned b2 = bf16_rne(r2);
        h0[e] = (short)b0; h1[e] = (short)b1; h2[e] = (short)b2;
    }
    *reinterpret_cast<short4*>(bsp + 0 * 262144 + base) = make_short4(h0[0], h0[1], h0[2], h0[3]);
    *reinterpret_cast<short4*>(bsp + 1 * 262144 + base) = make_short4(h1[0], h1[1], h1[2], h1[3]);
    *reinterpret_cast<short4*>(bsp + 2 * 262144 + base) = make_short4(h2[0], h2[1], h2[2], h2[3]);
}

// ================= GEMM: barrier-free bf16x3 split-product MFMA ===============
// Block = 32 token rows. Wave (ch,kh): 32 rows x 32 cols (ch half) over k-half
// kh (2048 k = 64 chunks of 32). A streams global->registers (in-register
// truncation split to 3 bf16 planes: exact cumulative representation);
// B fragments load from the L2-resident pre-split planes. NO barriers in the
// K-loop; one __syncthreads at the end combines the two k-half partials.
// Kept products a0b0,a0b1,a1b0,a1b1,a0b2,a2b0: neglected terms ~2^-24 rel.
__global__ __launch_bounds__(256) void gemm_bf16x3(const float* __restrict__ hid,
                                                   const short* __restrict__ bsp,
                                                   float* __restrict__ logits) {
    __shared__ float red[2][2][2][256];   // [ch][rt][ct][slot] kh=1 partials, 8 KB

    const int tid  = threadIdx.x;
    const int wv   = tid >> 6, lane = tid & 63;
    const int ch   = wv & 1;          // column half: cols 32*ch .. +31
    const int kh   = wv >> 1;         // k half: k in [2048*kh, 2048*kh+2048)
    const int r    = lane & 15;       // fragment free index
    const int q    = lane >> 4;       // k-slot group (8 k each)
    const int bm   = blockIdx.x * 32;

    // ---- C/D layout self-calibration (probe MFMAs; any bijective layout) ----
    const short hr  = (short)bf16_rne((float)r);
    const short one = (short)0x3F80;
    bf16x8 pav = {hr, hr, hr, hr, hr, hr, hr, hr};
    bf16x8 pbv = {one, one, one, one, one, one, one, one};
    f32x4 z = {0.f, 0.f, 0.f, 0.f};
    f32x4 rowp = __builtin_amdgcn_mfma_f32_16x16x32_bf16(pav, pbv, z, 0, 0, 0);
    f32x4 colp = __builtin_amdgcn_mfma_f32_16x16x32_bf16(pbv, pav, z, 0, 0, 0);
    int drow[4], dcol[4];
#pragma unroll
    for (int j = 0; j < 4; ++j) {
        drow[j] = (int)(rowp[j] * (1.f / 32.f) + 0.5f);
        dcol[j] = (int)(colp[j] * (1.f / 32.f) + 0.5f);
    }

    f32x4 acc[2][2] = {{z, z}, {z, z}};   // [row-tile][col-tile]

    // per-lane stream bases (A rows r and r+16; B cols 16*ct + r, 3 planes)
    const size_t kbase = (size_t)kh * 2048 + 8 * q;
    const float* aptr0 = hid + (size_t)(bm + r) * HDIM + kbase;
    const float* aptr1 = aptr0 + (size_t)16 * HDIM;
    const short* bptr[2][3];
#pragma unroll
    for (int ct = 0; ct < 2; ++ct)
#pragma unroll
        for (int s = 0; s < 3; ++s)
            bptr[ct][s] = bsp + ((size_t)s * NEXP + 32 * ch + 16 * ct + r) * HDIM + kbase;

    float4 aX[4], aY[4];      // raw A (2 rows x 8 k), named prefetch sets
    bf16x8 bX[2][3], bY[2][3];

#define LOADA(DST, C) do { \
        const int cc_ = ((C) < 64 ? (C) : 63) * 32; \
        DST[0] = *reinterpret_cast<const float4*>(aptr0 + cc_); \
        DST[1] = *reinterpret_cast<const float4*>(aptr0 + cc_ + 4); \
        DST[2] = *reinterpret_cast<const float4*>(aptr1 + cc_); \
        DST[3] = *reinterpret_cast<const float4*>(aptr1 + cc_ + 4); \
    } while (0)

#define LOADB(DST, C) do { \
        const int cc_ = ((C) < 64 ? (C) : 63) * 32; \
        _Pragma("unroll") \
        for (int ct_ = 0; ct_ < 2; ++ct_) \
        { _Pragma("unroll") \
          for (int s_ = 0; s_ < 3; ++s_) \
            DST[ct_][s_] = *reinterpret_cast<const bf16x8*>(bptr[ct_][s_] + cc_); } \
    } while (0)

    // in-register truncation split: f = p0 + p1 + p2 + r3, |r3| <= 2^-24 |f|
#define SPLIT8(LO, HI, P0, P1, P2) do { \
        float f_[8] = {LO.x, LO.y, LO.z, LO.w, HI.x, HI.y, HI.z, HI.w}; \
        unsigned u0_[8], u1_[8], u2_[8]; \
        _Pragma("unroll") \
        for (int i_ = 0; i_ < 8; ++i_) { \
            unsigned b0_ = __float_as_uint(f_[i_]) & 0xFFFF0000u; \
            float r1_ = f_[i_] - __uint_as_float(b0_); \
            unsigned b1_ = __float_as_uint(r1_) & 0xFFFF0000u; \
            float r2_ = r1_ - __uint_as_float(b1_); \
            u0_[i_] = b0_; u1_[i_] = b1_; \
            u2_[i_] = __float_as_uint(r2_) & 0xFFFF0000u; } \
        int4 w0_, w1_, w2_; \
        w0_.x = (int)((u0_[0] >> 16) | u0_[1]); w0_.y = (int)((u0_[2] >> 16) | u0_[3]); \
        w0_.z = (int)((u0_[4] >> 16) | u0_[5]); w0_.w = (int)((u0_[6] >> 16) | u0_[7]); \
        w1_.x = (int)((u1_[0] >> 16) | u1_[1]); w1_.y = (int)((u1_[2] >> 16) | u1_[3]); \
        w1_.z = (int)((u1_[4] >> 16) | u1_[5]); w1_.w = (int)((u1_[6] >> 16) | u1_[7]); \
        w2_.x = (int)((u2_[0] >> 16) | u2_[1]); w2_.y = (int)((u2_[2] >> 16) | u2_[3]); \
        w2_.z = (int)((u2_[4] >> 16) | u2_[5]); w2_.w = (int)((u2_[6] >> 16) | u2_[7]); \
        P0 = *reinterpret_cast<bf16x8*>(&w0_); \
        P1 = *reinterpret_cast<bf16x8*>(&w1_); \
        P2 = *reinterpret_cast<bf16x8*>(&w2_); \
    } while (0)

#define COMPUTE(A, B) do { \
        bf16x8 a00_, a01_, a02_, a10_, a11_, a12_; \
        SPLIT8(A[0], A[1], a00_, a01_, a02_); \
        SPLIT8(A[2], A[3], a10_, a11_, a12_); \
        _Pragma("unroll") \
        for (int ct_ = 0; ct_ < 2; ++ct_) { \
            acc[0][ct_] = __builtin_amdgcn_mfma_f32_16x16x32_bf16(a00_, B[ct_][0], acc[0][ct_], 0, 0, 0); \
            acc[1][ct_] = __builtin_amdgcn_mfma_f32_16x16x32_bf16(a10_, B[ct_][0], acc[1][ct_], 0, 0, 0); \
            acc[0][ct_] = __builtin_amdgcn_mfma_f32_16x16x32_bf16(a00_, B[ct_][1], acc[0][ct_], 0, 0, 0); \
            acc[1][ct_] = __builtin_amdgcn_mfma_f32_16x16x32_bf16(a10_, B[ct_][1], acc[1][ct_], 0, 0, 0); \
            acc[0][ct_] = __builtin_amdgcn_mfma_f32_16x16x32_bf16(a01_, B[ct_][0], acc[0][ct_], 0, 0, 0); \
            acc[1][ct_] = __builtin_amdgcn_mfma_f32_16x16x32_bf16(a11_, B[ct_][0], acc[1][ct_], 0, 0, 0); \
            acc[0][ct_] = __builtin_amdgcn_mfma_f32_16x16x32_bf16(a01_, B[ct_][1], acc[0][ct_], 0, 0, 0); \
            acc[1][ct_] = __builtin_amdgcn_mfma_f32_16x16x32_bf16(a11_, B[ct_][1], acc[1][ct_], 0, 0, 0); \
            acc[0][ct_] = __builtin_amdgcn_mfma_f32_16x16x32_bf16(a02_, B[ct_][0], acc[0][ct_], 0, 0, 0); \
            acc[1][ct_] = __builtin_amdgcn_mfma_f32_16x16x32_bf16(a12_, B[ct_][0], acc[1][ct_], 0, 0, 0); \
            acc[0][ct_] = __builtin_amdgcn_mfma_f32_16x16x32_bf16(a00_, B[ct_][2], acc[0][ct_], 0, 0, 0); \
            acc[1][ct_] = __builtin_amdgcn_mfma_f32_16x16x32_bf16(a10_, B[ct_][2], acc[1][ct_], 0, 0, 0); \
        } \
    } while (0)

    // ---- prologue + barrier-free main loop (64 chunks per wave) ----
    LOADA(aX, 0); LOADB(bX, 0);
    LOADA(aY, 1); LOADB(bY, 1);
    for (int c = 0; c < 64; c += 2) {
        COMPUTE(aX, bX);
        LOADA(aX, c + 2); LOADB(bX, c + 2);
        COMPUTE(aY, bY);
        LOADA(aY, c + 3); LOADB(bY, c + 3);
    }

#undef LOADA
#undef LOADB
#undef SPLIT8
#undef COMPUTE

    // ---- combine k-half partials, probe-derived scatter ----
    if (kh == 1) {
#pragma unroll
        for (int rt = 0; rt < 2; ++rt)
#pragma unroll
            for (int ct = 0; ct < 2; ++ct)
#pragma unroll
                for (int j = 0; j < 4; ++j)
                    red[ch][rt][ct][drow[j] * 16 + dcol[j]] = acc[rt][ct][j];
    }
    __syncthreads();
    if (kh == 0) {
#pragma unroll
        for (int rt = 0; rt < 2; ++rt)
#pragma unroll
            for (int ct = 0; ct < 2; ++ct)
#pragma unroll
                for (int j = 0; j < 4; ++j) {
                    const float v = acc[rt][ct][j] + red[ch][rt][ct][drow[j] * 16 + dcol[j]];
                    logits[(size_t)(bm + 16 * rt + drow[j]) * NEXP + 32 * ch + 16 * ct + dcol[j]] = v;
                }
    }
}

// ======== top-k + softmax + margin certification (one wave per token) =========
__global__ __launch_bounds__(256) void topk_margin(const float* __restrict__ logits,
                                                   float* __restrict__ out_idx,
                                                   float* __restrict__ out_w,
                                                   int* __restrict__ cnt,
                                                   int* __restrict__ list) {
    const int wave  = threadIdx.x >> 6;
    const int lane  = threadIdx.x & 63;
    const int token = blockIdx.x * 4 + wave;
    if (token >= TOKENS) return;

    float v = logits[(size_t)token * NEXP + lane];

    float myval = 0.f; int myidx = 0; float max0 = 0.f;

#pragma unroll
    for (int k = 0; k < TOPK + 1; ++k) {       // top-9: rank-9 needed for margin
        float bv = v; int bi = lane;
#pragma unroll
        for (int off = 32; off > 0; off >>= 1) {   // argmax, tie -> lower index
            float ov = __shfl_xor(bv, off);
            int   oi = __shfl_xor(bi, off);
            if (ov > bv || (ov == bv && oi < bi)) { bv = ov; bi = oi; }
        }
        if (k == 0) max0 = bv;
        if (lane == k) { myval = bv; myidx = bi; }
        if (lane == bi) v = -INFINITY;
    }

    const float nxt = __shfl(myval, lane + 1);
    const bool  bad = (lane < TOPK) && (myval - nxt < TAU);
    const bool  flagged = __any(bad);

    float e = (lane < TOPK) ? expf(myval - max0) : 0.f;
    float s = e;
#pragma unroll
    for (int off = 4; off > 0; off >>= 1) s += __shfl_xor(s, off);

    if (lane < TOPK) {
        size_t o = (size_t)token * TOPK + lane;
        out_idx[o] = (float)myidx;
        out_w[o]   = e / s;
    }
    if (flagged && lane == 0) {
        int slot = atomicAdd(cnt, 1);
        if (slot < TOKENS) list[slot] = token;
    }
}

// ======== exact fp64 recheck of flagged tokens (ordering ground truth) ========
__global__ __launch_bounds__(256) void recheck_kernel(const float* __restrict__ hid,
                                                      const float* __restrict__ wgt,
                                                      const int* __restrict__ cnt,
                                                      const int* __restrict__ list,
                                                      float* __restrict__ out_idx,
                                                      float* __restrict__ out_w) {
    __shared__ double dlog[NEXP];
    const int tid  = threadIdx.x;
    const int wv   = tid >> 6, lane = tid & 63;
    const int eg   = lane >> 4;
    const int kl   = lane & 15;
    const int n    = *cnt;

    for (int it = blockIdx.x; it < n && it < TOKENS; it += gridDim.x) {
        const int token = list[it];
        const float* hrow = hid + (size_t)token * HDIM;
#pragma unroll 1
        for (int pass = 0; pass < 4; ++pass) {
            const int e = wv * 16 + pass * 4 + eg;
            const float* wrow = wgt + (size_t)e * HDIM;
            double p = 0.0;
            for (int k0 = kl * 4; k0 < HDIM; k0 += 64) {
                float4 hv = *reinterpret_cast<const float4*>(hrow + k0);
                float4 wl = *reinterpret_cast<const float4*>(wrow + k0);
                p = fma((double)hv.x, (double)wl.x, p);
                p = fma((double)hv.y, (double)wl.y, p);
                p = fma((double)hv.z, (double)wl.z, p);
                p = fma((double)hv.w, (double)wl.w, p);
            }
#pragma unroll
            for (int off = 8; off > 0; off >>= 1) p += __shfl_xor(p, off);
            if (kl == 0) dlog[e] = p;
        }
        __syncthreads();
        if (wv == 0) {
            double v = dlog[lane];
            double myval = 0.0; int myidx = 0; double m0 = 0.0;
#pragma unroll
            for (int k = 0; k < TOPK; ++k) {
                double bv = v; int bi = lane;
#pragma unroll
                for (int off = 32; off > 0; off >>= 1) {
                    double ov = __shfl_xor(bv, off);
                    int    oi = __shfl_xor(bi, off);
                    if (ov > bv || (ov == bv && oi < bi)) { bv = ov; bi = oi; }
                }
                if (k == 0) m0 = bv;
                if (lane == k) { myval = bv; myidx = bi; }
                if (lane == bi) v = -INFINITY;
            }
            double ee = (lane < TOPK) ? exp(myval - m0) : 0.0;
            double ss = ee;
#pragma unroll
            for (int off = 4; off > 0; off >>= 1) ss += __shfl_xor(ss, off);
            if (lane < TOPK) {
                size_t o = (size_t)token * TOPK + lane;
                out_idx[o] = (float)myidx;
                out_w[o]   = (float)(ee / ss);
            }
        }
        __syncthreads();
    }
}

extern "C" void kernel_launch(void* const* d_in, const int* in_sizes, int n_in,
                              void* d_out, int out_size, void* d_ws, size_t ws_size,
                              hipStream_t stream) {
    const float* hid = (const float*)d_in[0];
    const float* wgt = (const float*)d_in[1];

    float* logits  = (float*)d_out;
    float* out_idx = logits + (size_t)TOKENS * NEXP;
    float* out_w   = out_idx + (size_t)TOKENS * TOPK;

    short* bsp  = (short*)d_ws;                                  // 1.5 MB bf16 planes
    int*   cnt  = (int*)((char*)d_ws + 3 * NEXP * HDIM * 2);
    int*   list = cnt + 1;

    bsplit_kernel <<<256, 256, 0, stream>>>(wgt, bsp, cnt);
    gemm_bf16x3   <<<TOKENS / 32, 256, 0, stream>>>(hid, bsp, logits);
    topk_margin   <<<TOKENS / 4, 256, 0, stream>>>(logits, out_idx, out_w, cnt, list);
    recheck_kernel<<<256, 256, 0, stream>>>(hid, wgt, cnt, list, out_idx, out_w);
}

// Round 12
// 239.480 us; speedup vs baseline: 1.6049x; 1.6049x over previous
//
#include <hip/hip_runtime.h>
#include <math.h>

// Problem constants (B=4, S=4096, H=4096, E=64, top_k=8)
#define TOKENS 16384   // B*S
#define HDIM   4096
#define NEXP   64
#define TOPK   8

#define TAU 1.5e-4f    // certify margin; logit err RMS ~2e-6 -> TAU/2 = 37 sigma

#define CH  64         // chunks per wave (2048 k / 32)
#define CLC(C) ((C) < CH ? (C) : CH - 1)

typedef short bf16x8 __attribute__((ext_vector_type(8)));
typedef float f32x4  __attribute__((ext_vector_type(4)));

__device__ __forceinline__ unsigned bf16_rne(float f) {
    unsigned u = __float_as_uint(f);
    return (u + 0x7fffu + ((u >> 16) & 1u)) >> 16;
}
__device__ __forceinline__ float bf16_tof(unsigned h) { return __uint_as_float(h << 16); }

// ================= B pre-split: wgt fp32 -> 3 bf16 planes in d_ws ==============
__global__ __launch_bounds__(256) void bsplit_kernel(const float* __restrict__ wgt,
                                                     short* __restrict__ bsp,
                                                     int* __restrict__ cnt) {
    if (blockIdx.x == 0 && threadIdx.x == 0) *cnt = 0;
    const int base = 4 * (blockIdx.x * 256 + threadIdx.x);
    float4 w = *reinterpret_cast<const float4*>(wgt + base);
    float f[4] = {w.x, w.y, w.z, w.w};
    short h0[4], h1[4], h2[4];
#pragma unroll
    for (int e = 0; e < 4; ++e) {
        unsigned b0 = bf16_rne(f[e]); float r1 = f[e] - bf16_tof(b0);
        unsigned b1 = bf16_rne(r1);   float r2 = r1 - bf16_tof(b1);
        unsigned b2 = bf16_rne(r2);
        h0[e] = (short)b0; h1[e] = (short)b1; h2[e] = (short)b2;
    }
    *reinterpret_cast<short4*>(bsp + 0 * 262144 + base) = make_short4(h0[0], h0[1], h0[2], h0[3]);
    *reinterpret_cast<short4*>(bsp + 1 * 262144 + base) = make_short4(h1[0], h1[1], h1[2], h1[3]);
    *reinterpret_cast<short4*>(bsp + 2 * 262144 + base) = make_short4(h2[0], h2[1], h2[2], h2[3]);
}

// ============ GEMM: barrier-free streaming bf16x3 with global_load_lds =========
// Block = 64 tokens, 4 waves = 2 row-groups x 2 k-halves. Each wave: 32 rows x
// 64 cols x 2048 k, fully independent (no barriers in the K-loop). A stages
// direct-to-LDS (wave-private 4-buffer ring, pre-swizzled global source + XOR
// read -> 2-way banks = free). B prefetches to registers from the L2-resident
// split planes, 2 chunks deep, compiler-tracked. One counted s_waitcnt
// vmcnt(16) per chunk (= previous body's 16 ops stay in flight; never 0).
// K-halves combine through LDS at the end (2 barriers total).
__global__ __launch_bounds__(256) void gemm_bf16x3(const float* __restrict__ hid,
                                                   const short* __restrict__ bsp,
                                                   float* __restrict__ logits) {
    __shared__ float Al[4][4][2][512];   // [wave][buf][rowtile][16x32 swizzled] = 64 KB

    const int tid  = threadIdx.x;
    const int wv   = tid >> 6, lane = tid & 63;
    const int rg   = wv & 1;           // row-group: rows rg*32 .. +31
    const int kh   = wv >> 1;          // k-half: k in [2048*kh, +2048)
    const int r    = lane & 15;        // fragment free index
    const int q    = lane >> 4;        // k-slot group (8 k each)
    const int bm   = blockIdx.x * 64;

    // ---- C/D layout self-calibration (probe MFMAs; proven rounds 10/11) ----
    const short hr  = (short)bf16_rne((float)r);
    const short one = (short)0x3F80;
    bf16x8 pav = {hr, hr, hr, hr, hr, hr, hr, hr};
    bf16x8 pbv = {one, one, one, one, one, one, one, one};
    f32x4 z = {0.f, 0.f, 0.f, 0.f};
    f32x4 rowp = __builtin_amdgcn_mfma_f32_16x16x32_bf16(pav, pbv, z, 0, 0, 0);
    f32x4 colp = __builtin_amdgcn_mfma_f32_16x16x32_bf16(pbv, pav, z, 0, 0, 0);
    int drow[4], dcol[4];
#pragma unroll
    for (int j = 0; j < 4; ++j) {
        drow[j] = (int)(rowp[j] * (1.f / 32.f) + 0.5f);
        dcol[j] = (int)(colp[j] * (1.f / 32.f) + 0.5f);
    }

    f32x4 acc[2][4];                   // [rowtile][coltile]
#pragma unroll
    for (int rt = 0; rt < 2; ++rt)
#pragma unroll
        for (int ct = 0; ct < 4; ++ct) acc[rt][ct] = z;

    // A gllds source (pre-swizzled): inst (rt,j) lane i -> row rt*16+j*8+(i>>3),
    // float4-offset (i&7)^((i>>3)&7). Dest linear => LDS holds XOR-swizzled rows.
    const int srow = lane >> 3;
    const int sf4  = (lane & 7) ^ (srow & 7);
    const float* abase = hid + (size_t)(bm + rg * 32 + srow) * HDIM + kh * 2048 + 4 * sf4;

    // B per-lane base: col r, k-slot 8q within the k-half; (ct,pl) add uniform offsets
    const short* bbase = bsp + (size_t)r * HDIM + kh * 2048 + 8 * q;

    bf16x8 B0[4][3], B1[4][3];         // two named prefetch sets (depth 2)

#define ISSUEA(BUF, C) do { \
        _Pragma("unroll") \
        for (int rt_ = 0; rt_ < 2; ++rt_) \
        { _Pragma("unroll") \
          for (int j_ = 0; j_ < 2; ++j_) \
            __builtin_amdgcn_global_load_lds( \
                (const __attribute__((address_space(1))) void*)(abase + (size_t)(rt_ * 16 + j_ * 8) * HDIM + (C) * 32), \
                (__attribute__((address_space(3))) void*)&Al[wv][BUF][rt_][j_ * 256], \
                16, 0, 0); } \
    } while (0)

#define LOADB(SET, C) do { \
        _Pragma("unroll") \
        for (int ct_ = 0; ct_ < 4; ++ct_) \
        { _Pragma("unroll") \
          for (int s_ = 0; s_ < 3; ++s_) \
            SET[ct_][s_] = *reinterpret_cast<const bf16x8*>( \
                bbase + (size_t)(s_ * NEXP + ct_ * 16) * HDIM + (C) * 32); } \
    } while (0)

    // in-register truncation split: f = p0+p1+p2+r3, |r3| <= 2^-24 |f| (proven r11)
#define SPLIT8(LO, HI, P0, P1, P2) do { \
        float f_[8] = {LO.x, LO.y, LO.z, LO.w, HI.x, HI.y, HI.z, HI.w}; \
        unsigned u0_[8], u1_[8], u2_[8]; \
        _Pragma("unroll") \
        for (int i_ = 0; i_ < 8; ++i_) { \
            unsigned b0_ = __float_as_uint(f_[i_]) & 0xFFFF0000u; \
            float r1_ = f_[i_] - __uint_as_float(b0_); \
            unsigned b1_ = __float_as_uint(r1_) & 0xFFFF0000u; \
            float r2_ = r1_ - __uint_as_float(b1_); \
            u0_[i_] = b0_; u1_[i_] = b1_; \
            u2_[i_] = __float_as_uint(r2_) & 0xFFFF0000u; } \
        int4 w0_, w1_, w2_; \
        w0_.x = (int)((u0_[0] >> 16) | u0_[1]); w0_.y = (int)((u0_[2] >> 16) | u0_[3]); \
        w0_.z = (int)((u0_[4] >> 16) | u0_[5]); w0_.w = (int)((u0_[6] >> 16) | u0_[7]); \
        w1_.x = (int)((u1_[0] >> 16) | u1_[1]); w1_.y = (int)((u1_[2] >> 16) | u1_[3]); \
        w1_.z = (int)((u1_[4] >> 16) | u1_[5]); w1_.w = (int)((u1_[6] >> 16) | u1_[7]); \
        w2_.x = (int)((u2_[0] >> 16) | u2_[1]); w2_.y = (int)((u2_[2] >> 16) | u2_[3]); \
        w2_.z = (int)((u2_[4] >> 16) | u2_[5]); w2_.w = (int)((u2_[6] >> 16) | u2_[7]); \
        P0 = *reinterpret_cast<bf16x8*>(&w0_); \
        P1 = *reinterpret_cast<bf16x8*>(&w1_); \
        P2 = *reinterpret_cast<bf16x8*>(&w2_); \
    } while (0)

#define COMPUTE(BUF, BS) do { \
        bf16x8 a0_[2], a1_[2], a2_[2]; \
        _Pragma("unroll") \
        for (int rt_ = 0; rt_ < 2; ++rt_) { \
            const float* ab_ = &Al[wv][BUF][rt_][r * 32]; \
            float4 lo_ = *reinterpret_cast<const float4*>(ab_ + 4 * ((2 * q) ^ (r & 7))); \
            float4 hi_ = *reinterpret_cast<const float4*>(ab_ + 4 * ((2 * q + 1) ^ (r & 7))); \
            SPLIT8(lo_, hi_, a0_[rt_], a1_[rt_], a2_[rt_]); \
        } \
        _Pragma("unroll") \
        for (int ct_ = 0; ct_ < 4; ++ct_) \
        { _Pragma("unroll") \
          for (int rt_ = 0; rt_ < 2; ++rt_) { \
            acc[rt_][ct_] = __builtin_amdgcn_mfma_f32_16x16x32_bf16(a0_[rt_], BS[ct_][0], acc[rt_][ct_], 0, 0, 0); \
            acc[rt_][ct_] = __builtin_amdgcn_mfma_f32_16x16x32_bf16(a0_[rt_], BS[ct_][1], acc[rt_][ct_], 0, 0, 0); \
            acc[rt_][ct_] = __builtin_amdgcn_mfma_f32_16x16x32_bf16(a1_[rt_], BS[ct_][0], acc[rt_][ct_], 0, 0, 0); \
            acc[rt_][ct_] = __builtin_amdgcn_mfma_f32_16x16x32_bf16(a1_[rt_], BS[ct_][1], acc[rt_][ct_], 0, 0, 0); \
            acc[rt_][ct_] = __builtin_amdgcn_mfma_f32_16x16x32_bf16(a0_[rt_], BS[ct_][2], acc[rt_][ct_], 0, 0, 0); \
            acc[rt_][ct_] = __builtin_amdgcn_mfma_f32_16x16x32_bf16(a2_[rt_], BS[ct_][0], acc[rt_][ct_], 0, 0, 0); \
          } } \
    } while (0)

    // ---- prologue: FIFO order [A0, B0, A1, B1, A2], pinned ----
    ISSUEA(0, 0);          __builtin_amdgcn_sched_barrier(0);
    LOADB(B0, 0);          __builtin_amdgcn_sched_barrier(0);
    ISSUEA(1, 1);          __builtin_amdgcn_sched_barrier(0);
    LOADB(B1, 1);          __builtin_amdgcn_sched_barrier(0);
    ISSUEA(2, 2);          __builtin_amdgcn_sched_barrier(0);

    // ---- barrier-free main loop: per half-body issue [B:12, A:4], wait 16 ----
    for (int c = 0; c < CH; c += 2) {
        asm volatile("s_waitcnt vmcnt(16)" ::: "memory");
        __builtin_amdgcn_sched_barrier(0);
        COMPUTE(c & 3, B0);
        LOADB(B0, CLC(c + 2));
        __builtin_amdgcn_sched_barrier(0);
        ISSUEA((c + 3) & 3, CLC(c + 3));
        __builtin_amdgcn_sched_barrier(0);

        asm volatile("s_waitcnt vmcnt(16)" ::: "memory");
        __builtin_amdgcn_sched_barrier(0);
        COMPUTE((c + 1) & 3, B1);
        LOADB(B1, CLC(c + 3));
        __builtin_amdgcn_sched_barrier(0);
        ISSUEA((c + 4) & 3, CLC(c + 4));
        __builtin_amdgcn_sched_barrier(0);
    }

#undef ISSUEA
#undef LOADB
#undef SPLIT8
#undef COMPUTE

    // ---- k-half reduction via LDS (aliases Al; all gllds drained by barrier) ----
    float* redp = &Al[0][0][0][0];     // 64 x 64 fp32 = 16 KB
    __syncthreads();                   // drains every wave's vmcnt before reuse
    if (kh == 1) {
#pragma unroll
        for (int rt = 0; rt < 2; ++rt)
#pragma unroll
            for (int ct = 0; ct < 4; ++ct)
#pragma unroll
                for (int j = 0; j < 4; ++j)
                    redp[(rg * 32 + rt * 16 + drow[j]) * 64 + ct * 16 + dcol[j]] = acc[rt][ct][j];
    }
    __syncthreads();
    if (kh == 0) {
#pragma unroll
        for (int rt = 0; rt < 2; ++rt)
#pragma unroll
            for (int ct = 0; ct < 4; ++ct)
#pragma unroll
                for (int j = 0; j < 4; ++j) {
                    const int row = rg * 32 + rt * 16 + drow[j];
                    const int col = ct * 16 + dcol[j];
                    logits[(size_t)(bm + row) * NEXP + col] = acc[rt][ct][j] + redp[row * 64 + col];
                }
    }
}

// ======== top-k + softmax + margin certification (one wave per token) =========
__global__ __launch_bounds__(256) void topk_margin(const float* __restrict__ logits,
                                                   float* __restrict__ out_idx,
                                                   float* __restrict__ out_w,
                                                   int* __restrict__ cnt,
                                                   int* __restrict__ list) {
    const int wave  = threadIdx.x >> 6;
    const int lane  = threadIdx.x & 63;
    const int token = blockIdx.x * 4 + wave;
    if (token >= TOKENS) return;

    float v = logits[(size_t)token * NEXP + lane];

    float myval = 0.f; int myidx = 0; float max0 = 0.f;

#pragma unroll
    for (int k = 0; k < TOPK + 1; ++k) {       // top-9: rank-9 needed for margin
        float bv = v; int bi = lane;
#pragma unroll
        for (int off = 32; off > 0; off >>= 1) {   // argmax, tie -> lower index
            float ov = __shfl_xor(bv, off);
            int   oi = __shfl_xor(bi, off);
            if (ov > bv || (ov == bv && oi < bi)) { bv = ov; bi = oi; }
        }
        if (k == 0) max0 = bv;
        if (lane == k) { myval = bv; myidx = bi; }
        if (lane == bi) v = -INFINITY;
    }

    const float nxt = __shfl(myval, lane + 1);
    const bool  bad = (lane < TOPK) && (myval - nxt < TAU);
    const bool  flagged = __any(bad);

    float e = (lane < TOPK) ? expf(myval - max0) : 0.f;
    float s = e;
#pragma unroll
    for (int off = 4; off > 0; off >>= 1) s += __shfl_xor(s, off);

    if (lane < TOPK) {
        size_t o = (size_t)token * TOPK + lane;
        out_idx[o] = (float)myidx;
        out_w[o]   = e / s;
    }
    if (flagged && lane == 0) {
        int slot = atomicAdd(cnt, 1);
        if (slot < TOKENS) list[slot] = token;
    }
}

// ======== exact fp64 recheck of flagged tokens (ordering ground truth) ========
__global__ __launch_bounds__(256) void recheck_kernel(const float* __restrict__ hid,
                                                      const float* __restrict__ wgt,
                                                      const int* __restrict__ cnt,
                                                      const int* __restrict__ list,
                                                      float* __restrict__ out_idx,
                                                      float* __restrict__ out_w) {
    __shared__ double dlog[NEXP];
    const int tid  = threadIdx.x;
    const int wv   = tid >> 6, lane = tid & 63;
    const int eg   = lane >> 4;
    const int kl   = lane & 15;
    const int n    = *cnt;

    for (int it = blockIdx.x; it < n && it < TOKENS; it += gridDim.x) {
        const int token = list[it];
        const float* hrow = hid + (size_t)token * HDIM;
#pragma unroll 1
        for (int pass = 0; pass < 4; ++pass) {
            const int e = wv * 16 + pass * 4 + eg;
            const float* wrow = wgt + (size_t)e * HDIM;
            double p = 0.0;
            for (int k0 = kl * 4; k0 < HDIM; k0 += 64) {
                float4 hv = *reinterpret_cast<const float4*>(hrow + k0);
                float4 wl = *reinterpret_cast<const float4*>(wrow + k0);
                p = fma((double)hv.x, (double)wl.x, p);
                p = fma((double)hv.y, (double)wl.y, p);
                p = fma((double)hv.z, (double)wl.z, p);
                p = fma((double)hv.w, (double)wl.w, p);
            }
#pragma unroll
            for (int off = 8; off > 0; off >>= 1) p += __shfl_xor(p, off);
            if (kl == 0) dlog[e] = p;
        }
        __syncthreads();
        if (wv == 0) {
            double v = dlog[lane];
            double myval = 0.0; int myidx = 0; double m0 = 0.0;
#pragma unroll
            for (int k = 0; k < TOPK; ++k) {
                double bv = v; int bi = lane;
#pragma unroll
                for (int off = 32; off > 0; off >>= 1) {
                    double ov = __shfl_xor(bv, off);
                    int    oi = __shfl_xor(bi, off);
                    if (ov > bv || (ov == bv && oi < bi)) { bv = ov; bi = oi; }
                }
                if (k == 0) m0 = bv;
                if (lane == k) { myval = bv; myidx = bi; }
                if (lane == bi) v = -INFINITY;
            }
            double ee = (lane < TOPK) ? exp(myval - m0) : 0.0;
            double ss = ee;
#pragma unroll
            for (int off = 4; off > 0; off >>= 1) ss += __shfl_xor(ss, off);
            if (lane < TOPK) {
                size_t o = (size_t)token * TOPK + lane;
                out_idx[o] = (float)myidx;
                out_w[o]   = (float)(ee / ss);
            }
        }
        __syncthreads();
    }
}

extern "C" void kernel_launch(void* const* d_in, const int* in_sizes, int n_in,
                              void* d_out, int out_size, void* d_ws, size_t ws_size,
                              hipStream_t stream) {
    const float* hid = (const float*)d_in[0];
    const float* wgt = (const float*)d_in[1];

    float* logits  = (float*)d_out;
    float* out_idx = logits + (size_t)TOKENS * NEXP;
    float* out_w   = out_idx + (size_t)TOKENS * TOPK;

    short* bsp  = (short*)d_ws;                                  // 1.5 MB bf16 planes
    int*   cnt  = (int*)((char*)d_ws + 3 * NEXP * HDIM * 2);
    int*   list = cnt + 1;

    bsplit_kernel <<<256, 256, 0, stream>>>(wgt, bsp, cnt);
    gemm_bf16x3   <<<TOKENS / 64, 256, 0, stream>>>(hid, bsp, logits);
    topk_margin   <<<TOKENS / 4, 256, 0, stream>>>(logits, out_idx, out_w, cnt, list);
    recheck_kernel<<<256, 256, 0, stream>>>(hid, wgt, cnt, list, out_idx, out_w);
}

// Round 13
// 212.484 us; speedup vs baseline: 1.8088x; 1.1270x over previous
//
#include <hip/hip_runtime.h>
#include <math.h>

// Problem constants (B=4, S=4096, H=4096, E=64, top_k=8)
#define TOKENS 16384   // B*S
#define HDIM   4096
#define NEXP   64
#define TOPK   8

#define TAU 1.5e-4f    // certify margin; logit err RMS ~2e-6 -> TAU/2 = 37 sigma

#define BM  32
#define BK  64
#define NCH (HDIM / BK)          // 64 chunks
#define CLC(C) ((C) < NCH ? (C) : NCH - 1)

typedef short bf16x8 __attribute__((ext_vector_type(8)));
typedef float f32x4  __attribute__((ext_vector_type(4)));

__device__ __forceinline__ unsigned bf16_rne(float f) {
    unsigned u = __float_as_uint(f);
    return (u + 0x7fffu + ((u >> 16) & 1u)) >> 16;
}
__device__ __forceinline__ float bf16_tof(unsigned h) { return __uint_as_float(h << 16); }

// ================= B pre-split: wgt fp32 -> 3 bf16 planes in d_ws ==============
__global__ __launch_bounds__(256) void bsplit_kernel(const float* __restrict__ wgt,
                                                     short* __restrict__ bsp,
                                                     int* __restrict__ cnt) {
    if (blockIdx.x == 0 && threadIdx.x == 0) *cnt = 0;
    const int base = 4 * (blockIdx.x * 256 + threadIdx.x);
    float4 w = *reinterpret_cast<const float4*>(wgt + base);
    float f[4] = {w.x, w.y, w.z, w.w};
    short h0[4], h1[4], h2[4];
#pragma unroll
    for (int e = 0; e < 4; ++e) {
        unsigned b0 = bf16_rne(f[e]); float r1 = f[e] - bf16_tof(b0);
        unsigned b1 = bf16_rne(r1);   float r2 = r1 - bf16_tof(b1);
        unsigned b2 = bf16_rne(r2);
        h0[e] = (short)b0; h1[e] = (short)b1; h2[e] = (short)b2;
    }
    *reinterpret_cast<short4*>(bsp + 0 * 262144 + base) = make_short4(h0[0], h0[1], h0[2], h0[3]);
    *reinterpret_cast<short4*>(bsp + 1 * 262144 + base) = make_short4(h1[0], h1[1], h1[2], h1[3]);
    *reinterpret_cast<short4*>(bsp + 2 * 262144 + base) = make_short4(h2[0], h2[1], h2[2], h2[3]);
}

// ========== GEMM: r5-skeleton (1 barrier/chunk) + bf16x3 MFMA engine ==========
// Block = 32 tokens, 4 waves; wave wv = all 32 rows x cols [16wv,16wv+16).
// Per chunk (BK=64): A fp32 global->regs (2-deep named prefetch, issued at body
// top) -> split to bf16x3 at staging -> swizzled LDS (double-buffered, 30.7 KB);
// B bf16x8 fragments straight from the L2-resident split planes (1-deep named
// prefetch). One __syncthreads per chunk; write-after-compute into the spare
// buffer (r5-proven). Products a0b0,a0b1,a1b0,a1b1,a0b2,a2b0 (fp32 acc);
// certified by TAU-margin + fp64 recheck downstream (passed r10-r12).
__global__ __launch_bounds__(256) void gemm_bf16x3(const float* __restrict__ hid,
                                                   const short* __restrict__ bsp,
                                                   float* __restrict__ logits) {
    __shared__ __align__(16) short Abf[2][3][2][32][40];  // [buf][plane][ksub][row][40]

    const int tid  = threadIdx.x;
    const int wv   = tid >> 6, lane = tid & 63;
    const int r    = lane & 15;       // fragment free index
    const int q    = lane >> 4;       // k-slot group (8 k each)
    const int bm   = blockIdx.x * BM;

    // ---- C/D layout self-calibration (probe MFMAs; proven rounds 10-12) ----
    const short hr  = (short)bf16_rne((float)r);
    const short one = (short)0x3F80;
    bf16x8 pav = {hr, hr, hr, hr, hr, hr, hr, hr};
    bf16x8 pbv = {one, one, one, one, one, one, one, one};
    f32x4 z = {0.f, 0.f, 0.f, 0.f};
    f32x4 rowp = __builtin_amdgcn_mfma_f32_16x16x32_bf16(pav, pbv, z, 0, 0, 0);
    f32x4 colp = __builtin_amdgcn_mfma_f32_16x16x32_bf16(pbv, pav, z, 0, 0, 0);
    int drow[4], dcol[4];
#pragma unroll
    for (int j = 0; j < 4; ++j) {
        drow[j] = (int)(rowp[j] * (1.f / 32.f) + 0.5f);
        dcol[j] = (int)(colp[j] * (1.f / 32.f) + 0.5f);
    }

    f32x4 acc[2] = {z, z};            // [row-tile 0/1], 16 cols each

    // staging: thread t -> row t>>3, 8-float k-group t&7 of the 32x64 A chunk
    const int srow = tid >> 3;
    const int sk8  = tid & 7;
    const int sks  = sk8 >> 2;                 // ksub 0/1
    const int swu  = (sk8 & 3) ^ (srow & 3);   // XOR-swizzled 16B unit
    const float* asrc = hid + (size_t)(bm + srow) * HDIM + 8 * sk8;

    // B per-lane plane pointers (col = 16wv + r)
    const short* bp0 = bsp + ((size_t)0 * NEXP + 16 * wv + r) * HDIM + 8 * q;
    const short* bp1 = bp0 + (size_t)NEXP * HDIM;
    const short* bp2 = bp1 + (size_t)NEXP * HDIM;

    float4 paX[2], paY[2];            // A raw prefetch (named sets, depth 2)
    bf16x8 BX[2][3], BY[2][3];        // B fragment sets [ksub][plane], depth 2

#define LOADA(P, C) do { \
        P[0] = *reinterpret_cast<const float4*>(asrc + CLC(C) * 64); \
        P[1] = *reinterpret_cast<const float4*>(asrc + CLC(C) * 64 + 4); \
    } while (0)

#define LOADB(S, C) do { \
        _Pragma("unroll") \
        for (int ks_ = 0; ks_ < 2; ++ks_) { \
            S[ks_][0] = *reinterpret_cast<const bf16x8*>(bp0 + CLC(C) * 64 + 32 * ks_); \
            S[ks_][1] = *reinterpret_cast<const bf16x8*>(bp1 + CLC(C) * 64 + 32 * ks_); \
            S[ks_][2] = *reinterpret_cast<const bf16x8*>(bp2 + CLC(C) * 64 + 32 * ks_); \
        } \
    } while (0)

    // split 8 fp32 -> 3 bf16 planes, one b128 LDS write per plane (swizzled unit)
#define SPLITW(P, BUF) do { \
        float f_[8] = {P[0].x, P[0].y, P[0].z, P[0].w, P[1].x, P[1].y, P[1].z, P[1].w}; \
        bf16x8 v0_, v1_, v2_; \
        _Pragma("unroll") \
        for (int i_ = 0; i_ < 8; ++i_) { \
            unsigned b0_ = __float_as_uint(f_[i_]) & 0xFFFF0000u; \
            float r1_ = f_[i_] - __uint_as_float(b0_); \
            unsigned b1_ = __float_as_uint(r1_) & 0xFFFF0000u; \
            float r2_ = r1_ - __uint_as_float(b1_); \
            unsigned b2_ = __float_as_uint(r2_) & 0xFFFF0000u; \
            v0_[i_] = (short)(b0_ >> 16); v1_[i_] = (short)(b1_ >> 16); v2_[i_] = (short)(b2_ >> 16); } \
        *reinterpret_cast<bf16x8*>(&Abf[BUF][0][sks][srow][8 * swu]) = v0_; \
        *reinterpret_cast<bf16x8*>(&Abf[BUF][1][sks][srow][8 * swu]) = v1_; \
        *reinterpret_cast<bf16x8*>(&Abf[BUF][2][sks][srow][8 * swu]) = v2_; \
    } while (0)

#define COMPUTE(BUF, BS) do { \
        _Pragma("unroll") \
        for (int ks_ = 0; ks_ < 2; ++ks_) \
        { _Pragma("unroll") \
          for (int rt_ = 0; rt_ < 2; ++rt_) { \
            const int ro_ = rt_ * 16 + r, ku_ = 8 * (q ^ (r & 3)); \
            bf16x8 a0_ = *reinterpret_cast<const bf16x8*>(&Abf[BUF][0][ks_][ro_][ku_]); \
            bf16x8 a1_ = *reinterpret_cast<const bf16x8*>(&Abf[BUF][1][ks_][ro_][ku_]); \
            bf16x8 a2_ = *reinterpret_cast<const bf16x8*>(&Abf[BUF][2][ks_][ro_][ku_]); \
            acc[rt_] = __builtin_amdgcn_mfma_f32_16x16x32_bf16(a0_, BS[ks_][0], acc[rt_], 0, 0, 0); \
            acc[rt_] = __builtin_amdgcn_mfma_f32_16x16x32_bf16(a0_, BS[ks_][1], acc[rt_], 0, 0, 0); \
            acc[rt_] = __builtin_amdgcn_mfma_f32_16x16x32_bf16(a1_, BS[ks_][0], acc[rt_], 0, 0, 0); \
            acc[rt_] = __builtin_amdgcn_mfma_f32_16x16x32_bf16(a1_, BS[ks_][1], acc[rt_], 0, 0, 0); \
            acc[rt_] = __builtin_amdgcn_mfma_f32_16x16x32_bf16(a0_, BS[ks_][2], acc[rt_], 0, 0, 0); \
            acc[rt_] = __builtin_amdgcn_mfma_f32_16x16x32_bf16(a2_, BS[ks_][0], acc[rt_], 0, 0, 0); \
          } } \
    } while (0)

    // ---- prologue: chunk 0 staged; A(1) in paX; B(0) in BX ----
    LOADA(paX, 0);
    SPLITW(paX, 0);
    LOADA(paX, 1);
    LOADB(BX, 0);

    // invariant at even-body top: LDS[0]=chunk c, paX=A(c+1), BX=B(c)
    for (int c = 0; c < NCH; c += 2) {
        __syncthreads();                 // LDS[0] ready
        LOADB(BY, c + 1);                // B(c+1)
        LOADA(paY, c + 2);               // A(c+2)  (issued at top -> drain ~free)
        COMPUTE(0, BX);                  // chunk c
        SPLITW(paX, 1);                  // A(c+1) -> LDS[1]

        __syncthreads();                 // LDS[1] ready
        LOADB(BX, c + 2);                // B(c+2)
        LOADA(paX, c + 3);               // A(c+3)
        COMPUTE(1, BY);                  // chunk c+1
        SPLITW(paY, 0);                  // A(c+2) -> LDS[0]
    }

#undef LOADA
#undef LOADB
#undef SPLITW
#undef COMPUTE

    // ---- epilogue: probe-derived scatter ----
#pragma unroll
    for (int rt = 0; rt < 2; ++rt)
#pragma unroll
        for (int j = 0; j < 4; ++j)
            logits[(size_t)(bm + rt * 16 + drow[j]) * NEXP + 16 * wv + dcol[j]] = acc[rt][j];
}

// ======== top-k + softmax + margin certification (one wave per token) =========
__global__ __launch_bounds__(256) void topk_margin(const float* __restrict__ logits,
                                                   float* __restrict__ out_idx,
                                                   float* __restrict__ out_w,
                                                   int* __restrict__ cnt,
                                                   int* __restrict__ list) {
    const int wave  = threadIdx.x >> 6;
    const int lane  = threadIdx.x & 63;
    const int token = blockIdx.x * 4 + wave;
    if (token >= TOKENS) return;

    float v = logits[(size_t)token * NEXP + lane];

    float myval = 0.f; int myidx = 0; float max0 = 0.f;

#pragma unroll
    for (int k = 0; k < TOPK + 1; ++k) {       // top-9: rank-9 needed for margin
        float bv = v; int bi = lane;
#pragma unroll
        for (int off = 32; off > 0; off >>= 1) {   // argmax, tie -> lower index
            float ov = __shfl_xor(bv, off);
            int   oi = __shfl_xor(bi, off);
            if (ov > bv || (ov == bv && oi < bi)) { bv = ov; bi = oi; }
        }
        if (k == 0) max0 = bv;
        if (lane == k) { myval = bv; myidx = bi; }
        if (lane == bi) v = -INFINITY;
    }

    const float nxt = __shfl(myval, lane + 1);
    const bool  bad = (lane < TOPK) && (myval - nxt < TAU);
    const bool  flagged = __any(bad);

    float e = (lane < TOPK) ? expf(myval - max0) : 0.f;
    float s = e;
#pragma unroll
    for (int off = 4; off > 0; off >>= 1) s += __shfl_xor(s, off);

    if (lane < TOPK) {
        size_t o = (size_t)token * TOPK + lane;
        out_idx[o] = (float)myidx;
        out_w[o]   = e / s;
    }
    if (flagged && lane == 0) {
        int slot = atomicAdd(cnt, 1);
        if (slot < TOKENS) list[slot] = token;
    }
}

// ======== exact fp64 recheck of flagged tokens (ordering ground truth) ========
__global__ __launch_bounds__(256) void recheck_kernel(const float* __restrict__ hid,
                                                      const float* __restrict__ wgt,
                                                      const int* __restrict__ cnt,
                                                      const int* __restrict__ list,
                                                      float* __restrict__ out_idx,
                                                      float* __restrict__ out_w) {
    __shared__ double dlog[NEXP];
    const int tid  = threadIdx.x;
    const int wv   = tid >> 6, lane = tid & 63;
    const int eg   = lane >> 4;
    const int kl   = lane & 15;
    const int n    = *cnt;

    for (int it = blockIdx.x; it < n && it < TOKENS; it += gridDim.x) {
        const int token = list[it];
        const float* hrow = hid + (size_t)token * HDIM;
#pragma unroll 1
        for (int pass = 0; pass < 4; ++pass) {
            const int e = wv * 16 + pass * 4 + eg;
            const float* wrow = wgt + (size_t)e * HDIM;
            double p = 0.0;
            for (int k0 = kl * 4; k0 < HDIM; k0 += 64) {
                float4 hv = *reinterpret_cast<const float4*>(hrow + k0);
                float4 wl = *reinterpret_cast<const float4*>(wrow + k0);
                p = fma((double)hv.x, (double)wl.x, p);
                p = fma((double)hv.y, (double)wl.y, p);
                p = fma((double)hv.z, (double)wl.z, p);
                p = fma((double)hv.w, (double)wl.w, p);
            }
#pragma unroll
            for (int off = 8; off > 0; off >>= 1) p += __shfl_xor(p, off);
            if (kl == 0) dlog[e] = p;
        }
        __syncthreads();
        if (wv == 0) {
            double v = dlog[lane];
            double myval = 0.0; int myidx = 0; double m0 = 0.0;
#pragma unroll
            for (int k = 0; k < TOPK; ++k) {
                double bv = v; int bi = lane;
#pragma unroll
                for (int off = 32; off > 0; off >>= 1) {
                    double ov = __shfl_xor(bv, off);
                    int    oi = __shfl_xor(bi, off);
                    if (ov > bv || (ov == bv && oi < bi)) { bv = ov; bi = oi; }
                }
                if (k == 0) m0 = bv;
                if (lane == k) { myval = bv; myidx = bi; }
                if (lane == bi) v = -INFINITY;
            }
            double ee = (lane < TOPK) ? exp(myval - m0) : 0.0;
            double ss = ee;
#pragma unroll
            for (int off = 4; off > 0; off >>= 1) ss += __shfl_xor(ss, off);
            if (lane < TOPK) {
                size_t o = (size_t)token * TOPK + lane;
                out_idx[o] = (float)myidx;
                out_w[o]   = (float)(ee / ss);
            }
        }
        __syncthreads();
    }
}

extern "C" void kernel_launch(void* const* d_in, const int* in_sizes, int n_in,
                              void* d_out, int out_size, void* d_ws, size_t ws_size,
                              hipStream_t stream) {
    const float* hid = (const float*)d_in[0];
    const float* wgt = (const float*)d_in[1];

    float* logits  = (float*)d_out;
    float* out_idx = logits + (size_t)TOKENS * NEXP;
    float* out_w   = out_idx + (size_t)TOKENS * TOPK;

    short* bsp  = (short*)d_ws;                                  // 1.5 MB bf16 planes
    int*   cnt  = (int*)((char*)d_ws + 3 * NEXP * HDIM * 2);
    int*   list = cnt + 1;

    bsplit_kernel <<<256, 256, 0, stream>>>(wgt, bsp, cnt);
    gemm_bf16x3   <<<TOKENS / BM, 256, 0, stream>>>(hid, bsp, logits);
    topk_margin   <<<TOKENS / 4, 256, 0, stream>>>(logits, out_idx, out_w, cnt, list);
    recheck_kernel<<<256, 256, 0, stream>>>(hid, wgt, cnt, list, out_idx, out_w);
}